// Round 3
// baseline (3968.930 us; speedup 1.0000x reference)
//
#include <hip/hip_runtime.h>
#include <stdint.h>

typedef int i32x4 __attribute__((ext_vector_type(4)));
typedef float f32x4 __attribute__((ext_vector_type(4)));

#define TWO_LOG2E 2.8853900817779268f

// ---------------- ws layout ----------------
// [0,8)            : thrbits[2] (uint, atomicMax of |w| bits)
// [4096, +16MB)    : Xq  [32768][512] int8
// then             : WriT [1024][512] int8  (n = dir*512 + j, k = i)
// then             : WrhT [2][512][512] int8 (row j, col i)
#define WS_XQ_OFF   4096
#define XQ_BYTES    ((size_t)32768 * 512)
#define WRIT_BYTES  ((size_t)1024 * 512)
#define WRHT_BYTES  ((size_t)2 * 512 * 512)

// ---------------- threshold = max |w| over [w_ri; w_rh] per direction ----------------
__global__ __launch_bounds__(256) void k_absmax(const float* __restrict__ wri_f,
                                                const float* __restrict__ wrh_f,
                                                const float* __restrict__ wri_b,
                                                const float* __restrict__ wrh_b,
                                                unsigned* thrbits) {
    int dir = blockIdx.y;
    const float* a = dir ? wri_b : wri_f;
    const float* c = dir ? wrh_b : wrh_f;
    float m = 0.f;
    for (int i = blockIdx.x * 256 + threadIdx.x; i < 512 * 512; i += gridDim.x * 256) {
        m = fmaxf(m, fabsf(a[i]));
        m = fmaxf(m, fabsf(c[i]));
    }
    __shared__ float red[256];
    red[threadIdx.x] = m;
    __syncthreads();
    for (int s = 128; s > 0; s >>= 1) {
        if (threadIdx.x < s) red[threadIdx.x] = fmaxf(red[threadIdx.x], red[threadIdx.x + s]);
        __syncthreads();
    }
    if (threadIdx.x == 0) atomicMax(&thrbits[dir], __float_as_uint(red[0]));
}

// ---------------- quantize weights + transpose (WT[j][i] = round(W[i][j]/s)) ----------------
__global__ __launch_bounds__(256) void k_quant_w(const float* __restrict__ wri_f,
                                                 const float* __restrict__ wrh_f,
                                                 const float* __restrict__ wri_b,
                                                 const float* __restrict__ wrh_b,
                                                 const unsigned* __restrict__ thrbits,
                                                 signed char* __restrict__ writ,
                                                 signed char* __restrict__ wrht) {
    int id = blockIdx.x;             // 256 blocks
    int dir = id & 1;
    int which = (id >> 1) & 1;       // 0 = ri, 1 = rh
    int tile = id >> 2;              // 0..63  (8x8 tiles of 64x64)
    int ti = tile >> 3, tj = tile & 7;
    const float* src = which ? (dir ? wrh_b : wrh_f) : (dir ? wri_b : wri_f);
    signed char* dst = which ? (wrht + (size_t)dir * 512 * 512) : (writ + (size_t)dir * 512 * 512);
    float s = __uint_as_float(thrbits[dir]) / 127.0f;
    __shared__ signed char t8[64][68];
    int tx = threadIdx.x & 63, ty = threadIdx.x >> 6;
    int i0 = ti * 64, j0 = tj * 64;
#pragma unroll
    for (int r = 0; r < 16; ++r) {
        int il = r * 4 + ty;
        float w = src[(size_t)(i0 + il) * 512 + j0 + tx];
        float q = rintf(w / s);
        q = fminf(fmaxf(q, -127.f), 127.f);
        t8[il][tx] = (signed char)(int)q;
    }
    __syncthreads();
#pragma unroll
    for (int r = 0; r < 16; ++r) {
        int jl = r * 4 + ty;
        dst[(size_t)(j0 + jl) * 512 + i0 + tx] = t8[tx][jl];  // WT[j][i]
    }
}

// ---------------- quantize inputs: xq = round(clip(x,-1,1)*127) ----------------
__global__ __launch_bounds__(256) void k_quant_x(const float* __restrict__ x,
                                                 signed char* __restrict__ xq) {
    int i = blockIdx.x * 256 + threadIdx.x;   // one float4 per thread, 16384 blocks
    float4 v = ((const float4*)x)[i];
    int q0 = (int)rintf(fminf(fmaxf(v.x, -1.f), 1.f) * 127.f);
    int q1 = (int)rintf(fminf(fmaxf(v.y, -1.f), 1.f) * 127.f);
    int q2 = (int)rintf(fminf(fmaxf(v.z, -1.f), 1.f) * 127.f);
    int q3 = (int)rintf(fminf(fmaxf(v.w, -1.f), 1.f) * 127.f);
    ((int*)xq)[i] = (q0 & 255) | ((q1 & 255) << 8) | ((q2 & 255) << 16) | ((q3 & 255) << 24);
}

// ---------------- GEMM: out[t*16+b][n] = (Xq . WriT[n]) * gs2 + b[n]*2log2e ----------------
__global__ __launch_bounds__(256, 2) void k_gemm_xif(const signed char* __restrict__ xq,
                                                     const signed char* __restrict__ writ,
                                                     const float* __restrict__ b_f,
                                                     const float* __restrict__ b_b,
                                                     const unsigned* __restrict__ thrbits,
                                                     float* __restrict__ out) {
    int bid = blockIdx.x;        // 2048 = 256 Mtiles * 8 Ntiles
    int mt8 = bid >> 3;
    int nt8 = bid & 7;
    int w = threadIdx.x >> 6, lane = threadIdx.x & 63;
    int l15 = lane & 15, q = lane >> 4;
    int M0 = mt8 * 128 + (w >> 1) * 64;
    int N0 = nt8 * 128 + (w & 1) * 64;
    int dir = N0 >> 9;
    float thr = __uint_as_float(thrbits[dir]);
    float gs2 = thr * (TWO_LOG2E / (127.f * 127.f));
    const float* bp = dir ? b_b : b_f;
    float bi2[4];
#pragma unroll
    for (int nt = 0; nt < 4; ++nt)
        bi2[nt] = bp[(N0 & 511) + nt * 16 + l15] * TWO_LOG2E;

    i32x4 acc[4][4];
#pragma unroll
    for (int mt = 0; mt < 4; ++mt)
#pragma unroll
        for (int nt = 0; nt < 4; ++nt)
            acc[mt][nt] = (i32x4){0, 0, 0, 0};

#pragma unroll
    for (int kb = 0; kb < 8; ++kb) {
        i32x4 af[4], bf[4];
#pragma unroll
        for (int mt = 0; mt < 4; ++mt)
            af[mt] = *(const i32x4*)(xq + (size_t)(M0 + mt * 16 + l15) * 512 + kb * 64 + q * 16);
#pragma unroll
        for (int nt = 0; nt < 4; ++nt)
            bf[nt] = *(const i32x4*)(writ + (size_t)(N0 + nt * 16 + l15) * 512 + kb * 64 + q * 16);
#pragma unroll
        for (int mt = 0; mt < 4; ++mt)
#pragma unroll
            for (int nt = 0; nt < 4; ++nt)
                acc[mt][nt] = __builtin_amdgcn_mfma_i32_16x16x64_i8(af[mt], bf[nt], acc[mt][nt], 0, 0, 0);
    }
#pragma unroll
    for (int mt = 0; mt < 4; ++mt)
#pragma unroll
        for (int nt = 0; nt < 4; ++nt)
#pragma unroll
            for (int r = 0; r < 4; ++r) {
                int row = M0 + mt * 16 + q * 4 + r;
                int col = N0 + nt * 16 + l15;
                out[(size_t)row * 1024 + col] = fmaf((float)acc[mt][nt][r], gs2, bi2[nt]);
            }
}

// ---------------- persistent recurrence: 1 WG per direction (2 WGs, 8 waves each) ----------------
// Swapped MFMA: gateT[n][b] = WrhT[n][k] (A, static VGPRs) x StT[k][b] (B, from LDS).
// Per step: 256 mfma_i32_16x16x64_i8 (zero waste: N=16 real batches, M=512 real cols).
// C/D: col = lane&15 -> batch, row = (lane>>4)*4+reg -> n within M-tile.
// h127 = rint(127 - 254/(1+exp2(acc*gs2 + xi))) via magic-add RNE; int8 state byte = low
// byte of the magic float's bits; state double-buffered in LDS [2][16][528].
__global__ __launch_bounds__(512, 2) void k_rnn(const signed char* __restrict__ wrht,
                                                const unsigned* __restrict__ thrbits,
                                                float* __restrict__ out) {
    int dir = blockIdx.x;           // 2 WGs
    int w = threadIdx.x >> 6, lane = threadIdx.x & 63;
    int l15 = lane & 15, q = lane >> 4;
    int n0 = w * 64;                // this wave's 64 output cols (4 M-tiles)
    float thr = __uint_as_float(thrbits[dir]);
    float gs2 = thr * (TWO_LOG2E / (127.f * 127.f));
    const signed char* wq = wrht + (size_t)dir * 512 * 512;

    // A-frags (weights) resident: 4 M-tiles x 8 kb x 16B = 128 VGPRs
    i32x4 a[4][8];
#pragma unroll
    for (int mt = 0; mt < 4; ++mt)
#pragma unroll
        for (int kb = 0; kb < 8; ++kb)
            a[mt][kb] = *(const i32x4*)(wq + (size_t)(n0 + mt * 16 + l15) * 512 + kb * 64 + q * 16);

    __shared__ __align__(16) signed char st[2][16][528];  // [buf][batch][k], 528 = 16*33 stride
    for (int i = threadIdx.x; i < 2 * 16 * 528 / 4; i += 512) ((int*)st)[i] = 0;
    __syncthreads();

    const int rs = 16 * 1024;                    // floats per timestep row-block
    int t0 = dir ? 2047 : 0;
    int tstep = dir ? -rs : rs;
    // this lane's 16 gate/out elements at time t: out[(t*16+l15)*1024 + dir*512 + n0 + mt*16 + q*4 + r]
    float* pbase = out + ((size_t)t0 * 16 + l15) * 1024 + dir * 512 + n0 + q * 4;

    f32x4 xi[4];
#pragma unroll
    for (int mt = 0; mt < 4; ++mt) xi[mt] = *(const f32x4*)(pbase + mt * 16);

    int pp = 0;
    for (int step = 0; step < 2048; ++step) {
        float* pnext = pbase + ((step + 1 < 2048) ? tstep : 0);
        f32x4 xin[4];
#pragma unroll
        for (int mt = 0; mt < 4; ++mt) xin[mt] = *(const f32x4*)(pnext + mt * 16);  // prefetch

        // B-frags: state, shared across waves (8 x ds_read_b128)
        i32x4 bf[8];
#pragma unroll
        for (int kb = 0; kb < 8; ++kb)
            bf[kb] = *(const i32x4*)&st[pp][l15][kb * 64 + q * 16];

        i32x4 acc[4];
#pragma unroll
        for (int mt = 0; mt < 4; ++mt) acc[mt] = (i32x4){0, 0, 0, 0};
#pragma unroll
        for (int kb = 0; kb < 8; ++kb)
#pragma unroll
            for (int mt = 0; mt < 4; ++mt)
                acc[mt] = __builtin_amdgcn_mfma_i32_16x16x64_i8(a[mt][kb], bf[kb], acc[mt], 0, 0, 0);

#pragma unroll
        for (int mt = 0; mt < 4; ++mt) {
            unsigned packed = 0;
            f32x4 ho;
#pragma unroll
            for (int r = 0; r < 4; ++r) {
                float arg = fmaf((float)acc[mt][r], gs2, xi[mt][r]);
                float e = __builtin_amdgcn_exp2f(arg);
                float rc = __builtin_amdgcn_rcpf(1.0f + e);
                float t = fmaf(rc, -254.0f, 127.0f);
                float mm = t + 12582912.0f;                    // RNE round, |t| <= 127
                packed |= (__float_as_uint(mm) & 0xFFu) << (8 * r);  // int8 two's complement
                ho[r] = (mm - 12582912.0f) * (1.0f / 127.0f);
            }
            *(f32x4*)(pbase + mt * 16) = ho;                        // h out (dwordx4)
            *(unsigned*)&st[pp ^ 1][l15][n0 + mt * 16 + q * 4] = packed;  // 4 state bytes
        }

#pragma unroll
        for (int mt = 0; mt < 4; ++mt) xi[mt] = xin[mt];
        pbase = pnext;
        // LDS-only barrier: don't drain vmcnt (out stores / prefetches stay in flight)
        asm volatile("s_waitcnt lgkmcnt(0)" ::: "memory");
        __builtin_amdgcn_s_barrier();
        __builtin_amdgcn_sched_barrier(0);
        pp ^= 1;
    }
}

extern "C" void kernel_launch(void* const* d_in, const int* in_sizes, int n_in,
                              void* d_out, int out_size, void* d_ws, size_t ws_size,
                              hipStream_t stream) {
    const float* x     = (const float*)d_in[0];
    const float* wri_f = (const float*)d_in[1];
    const float* wrh_f = (const float*)d_in[2];
    const float* b_f   = (const float*)d_in[3];
    const float* wri_b = (const float*)d_in[4];
    const float* wrh_b = (const float*)d_in[5];
    const float* b_b   = (const float*)d_in[6];
    float* out = (float*)d_out;
    char* ws = (char*)d_ws;

    size_t need = WS_XQ_OFF + XQ_BYTES + WRIT_BYTES + WRHT_BYTES;
    if (ws_size < need) return;

    unsigned* thrbits = (unsigned*)ws;
    signed char* xq   = (signed char*)(ws + WS_XQ_OFF);
    signed char* writ = xq + XQ_BYTES;
    signed char* wrht = writ + WRIT_BYTES;

    hipMemsetAsync(thrbits, 0, 8, stream);
    k_absmax<<<dim3(64, 2), 256, 0, stream>>>(wri_f, wrh_f, wri_b, wrh_b, thrbits);
    k_quant_w<<<256, 256, 0, stream>>>(wri_f, wrh_f, wri_b, wrh_b, thrbits, writ, wrht);
    k_quant_x<<<16384, 256, 0, stream>>>(x, xq);
    k_gemm_xif<<<2048, 256, 0, stream>>>(xq, writ, b_f, b_b, thrbits, out);
    k_rnn<<<2, 512, 0, stream>>>(wrht, thrbits, out);
}

// Round 4
// 3356.204 us; speedup vs baseline: 1.1826x; 1.1826x over previous
//
#include <hip/hip_runtime.h>
#include <stdint.h>

typedef int i32x4 __attribute__((ext_vector_type(4)));
typedef float f32x4 __attribute__((ext_vector_type(4)));

#define TWO_LOG2E 2.8853900817779268f

// ---------------- ws layout ----------------
#define WS_XQ_OFF   4096
#define XQ_BYTES    ((size_t)32768 * 512)
#define WRIT_BYTES  ((size_t)1024 * 512)
#define WRHT_BYTES  ((size_t)2 * 512 * 512)

// ---------------- threshold = max |w| over [w_ri; w_rh] per direction ----------------
__global__ __launch_bounds__(256) void k_absmax(const float* __restrict__ wri_f,
                                                const float* __restrict__ wrh_f,
                                                const float* __restrict__ wri_b,
                                                const float* __restrict__ wrh_b,
                                                unsigned* thrbits) {
    int dir = blockIdx.y;
    const float* a = dir ? wri_b : wri_f;
    const float* c = dir ? wrh_b : wrh_f;
    float m = 0.f;
    for (int i = blockIdx.x * 256 + threadIdx.x; i < 512 * 512; i += gridDim.x * 256) {
        m = fmaxf(m, fabsf(a[i]));
        m = fmaxf(m, fabsf(c[i]));
    }
    __shared__ float red[256];
    red[threadIdx.x] = m;
    __syncthreads();
    for (int s = 128; s > 0; s >>= 1) {
        if (threadIdx.x < s) red[threadIdx.x] = fmaxf(red[threadIdx.x], red[threadIdx.x + s]);
        __syncthreads();
    }
    if (threadIdx.x == 0) atomicMax(&thrbits[dir], __float_as_uint(red[0]));
}

// ---------------- quantize weights + transpose (WT[j][i] = round(W[i][j]/s)) ----------------
__global__ __launch_bounds__(256) void k_quant_w(const float* __restrict__ wri_f,
                                                 const float* __restrict__ wrh_f,
                                                 const float* __restrict__ wri_b,
                                                 const float* __restrict__ wrh_b,
                                                 const unsigned* __restrict__ thrbits,
                                                 signed char* __restrict__ writ,
                                                 signed char* __restrict__ wrht) {
    int id = blockIdx.x;             // 256 blocks
    int dir = id & 1;
    int which = (id >> 1) & 1;       // 0 = ri, 1 = rh
    int tile = id >> 2;              // 0..63  (8x8 tiles of 64x64)
    int ti = tile >> 3, tj = tile & 7;
    const float* src = which ? (dir ? wrh_b : wrh_f) : (dir ? wri_b : wri_f);
    signed char* dst = which ? (wrht + (size_t)dir * 512 * 512) : (writ + (size_t)dir * 512 * 512);
    float s = __uint_as_float(thrbits[dir]) / 127.0f;
    __shared__ signed char t8[64][68];
    int tx = threadIdx.x & 63, ty = threadIdx.x >> 6;
    int i0 = ti * 64, j0 = tj * 64;
#pragma unroll
    for (int r = 0; r < 16; ++r) {
        int il = r * 4 + ty;
        float w = src[(size_t)(i0 + il) * 512 + j0 + tx];
        float q = rintf(w / s);
        q = fminf(fmaxf(q, -127.f), 127.f);
        t8[il][tx] = (signed char)(int)q;
    }
    __syncthreads();
#pragma unroll
    for (int r = 0; r < 16; ++r) {
        int jl = r * 4 + ty;
        dst[(size_t)(j0 + jl) * 512 + i0 + tx] = t8[tx][jl];  // WT[j][i]
    }
}

// ---------------- quantize inputs: xq = round(clip(x,-1,1)*127) ----------------
__global__ __launch_bounds__(256) void k_quant_x(const float* __restrict__ x,
                                                 signed char* __restrict__ xq) {
    int i = blockIdx.x * 256 + threadIdx.x;   // one float4 per thread, 16384 blocks
    float4 v = ((const float4*)x)[i];
    int q0 = (int)rintf(fminf(fmaxf(v.x, -1.f), 1.f) * 127.f);
    int q1 = (int)rintf(fminf(fmaxf(v.y, -1.f), 1.f) * 127.f);
    int q2 = (int)rintf(fminf(fmaxf(v.z, -1.f), 1.f) * 127.f);
    int q3 = (int)rintf(fminf(fmaxf(v.w, -1.f), 1.f) * 127.f);
    ((int*)xq)[i] = (q0 & 255) | ((q1 & 255) << 8) | ((q2 & 255) << 16) | ((q3 & 255) << 24);
}

// ---------------- GEMM: out[t*16+b][n] = (Xq . WriT[n]) * gs2 + b[n]*2log2e ----------------
__global__ __launch_bounds__(256, 2) void k_gemm_xif(const signed char* __restrict__ xq,
                                                     const signed char* __restrict__ writ,
                                                     const float* __restrict__ b_f,
                                                     const float* __restrict__ b_b,
                                                     const unsigned* __restrict__ thrbits,
                                                     float* __restrict__ out) {
    int bid = blockIdx.x;        // 2048 = 256 Mtiles * 8 Ntiles
    int mt8 = bid >> 3;
    int nt8 = bid & 7;
    int w = threadIdx.x >> 6, lane = threadIdx.x & 63;
    int l15 = lane & 15, q = lane >> 4;
    int M0 = mt8 * 128 + (w >> 1) * 64;
    int N0 = nt8 * 128 + (w & 1) * 64;
    int dir = N0 >> 9;
    float thr = __uint_as_float(thrbits[dir]);
    float gs2 = thr * (TWO_LOG2E / (127.f * 127.f));
    const float* bp = dir ? b_b : b_f;
    float bi2[4];
#pragma unroll
    for (int nt = 0; nt < 4; ++nt)
        bi2[nt] = bp[(N0 & 511) + nt * 16 + l15] * TWO_LOG2E;

    i32x4 acc[4][4];
#pragma unroll
    for (int mt = 0; mt < 4; ++mt)
#pragma unroll
        for (int nt = 0; nt < 4; ++nt)
            acc[mt][nt] = (i32x4){0, 0, 0, 0};

#pragma unroll
    for (int kb = 0; kb < 8; ++kb) {
        i32x4 af[4], bf[4];
#pragma unroll
        for (int mt = 0; mt < 4; ++mt)
            af[mt] = *(const i32x4*)(xq + (size_t)(M0 + mt * 16 + l15) * 512 + kb * 64 + q * 16);
#pragma unroll
        for (int nt = 0; nt < 4; ++nt)
            bf[nt] = *(const i32x4*)(writ + (size_t)(N0 + nt * 16 + l15) * 512 + kb * 64 + q * 16);
#pragma unroll
        for (int mt = 0; mt < 4; ++mt)
#pragma unroll
            for (int nt = 0; nt < 4; ++nt)
                acc[mt][nt] = __builtin_amdgcn_mfma_i32_16x16x64_i8(af[mt], bf[nt], acc[mt][nt], 0, 0, 0);
    }
#pragma unroll
    for (int mt = 0; mt < 4; ++mt)
#pragma unroll
        for (int nt = 0; nt < 4; ++nt)
#pragma unroll
            for (int r = 0; r < 4; ++r) {
                int row = M0 + mt * 16 + q * 4 + r;
                int col = N0 + nt * 16 + l15;
                out[(size_t)row * 1024 + col] = fmaf((float)acc[mt][nt][r], gs2, bi2[nt]);
            }
}

// ---------------- persistent recurrence: 1 WG per direction, 1024 threads (16 waves) ----------
// Swapped MFMA: gateT[n][b] = WrhT[n][k] (A, 64 static VGPRs/wave) x StT[k][b] (B, LDS).
// 16 waves x 2 M-tiles = 512 n-cols; 256 mfma_i32_16x16x64_i8 per dir-step (zero waste).
// 4 waves/SIMD: MFMA latency hidden, epilogue VALU overlaps other waves' MFMA.
// h127 = rint(127 - 254/(1+exp2(acc*gs2 + xi))) via magic-add RNE; state bytes via v_perm.
__global__ __launch_bounds__(1024) void k_rnn(const signed char* __restrict__ wrht,
                                              const unsigned* __restrict__ thrbits,
                                              float* __restrict__ out) {
    int dir = blockIdx.x;           // 2 WGs
    int w = threadIdx.x >> 6, lane = threadIdx.x & 63;
    int l15 = lane & 15, q = lane >> 4;
    int n0 = w * 32;                // this wave's 32 output cols (2 M-tiles)
    float thr = __uint_as_float(thrbits[dir]);
    float gs2 = thr * (TWO_LOG2E / (127.f * 127.f));
    const signed char* wq = wrht + (size_t)dir * 512 * 512;

    // A-frags (weights) resident: 2 M-tiles x 8 kb x 16B = 64 VGPRs
    i32x4 a[2][8];
#pragma unroll
    for (int mt = 0; mt < 2; ++mt)
#pragma unroll
        for (int kb = 0; kb < 8; ++kb)
            a[mt][kb] = *(const i32x4*)(wq + (size_t)(n0 + mt * 16 + l15) * 512 + kb * 64 + q * 16);

    __shared__ __align__(16) signed char st[2][16][528];  // [buf][batch][k], stride 528
    for (int i = threadIdx.x; i < 2 * 16 * 528 / 4; i += 1024) ((int*)st)[i] = 0;
    __syncthreads();

    int t0 = dir ? 2047 : 0;
    int tstep = dir ? -16 * 1024 : 16 * 1024;
    // lane's 8 gate/out elements at time t: out[(t*16+l15)*1024 + dir*512 + n0 + mt*16 + q*4 + r]
    float* pbase = out + ((size_t)t0 * 16 + l15) * 1024 + dir * 512 + n0 + q * 4;

    f32x4 xi0 = *(const f32x4*)(pbase);
    f32x4 xi1 = *(const f32x4*)(pbase + 16);

    const signed char* spbase0 = &st[0][l15][q * 16];
    const signed char* spbase1 = &st[1][l15][q * 16];

    int pp = 0;
    for (int step = 0; step < 2048; ++step) {
        float* pnext = pbase + ((step + 1 < 2048) ? tstep : 0);
        const signed char* sp = pp ? spbase1 : spbase0;

        // rolling 4-deep B-frag window (16 VGPRs) interleaved with the MFMA stream
        i32x4 acc0 = (i32x4){0, 0, 0, 0}, acc1 = (i32x4){0, 0, 0, 0};
        i32x4 bfr[4];
        bfr[0] = *(const i32x4*)(sp);
        bfr[1] = *(const i32x4*)(sp + 64);
        bfr[2] = *(const i32x4*)(sp + 128);
        bfr[3] = *(const i32x4*)(sp + 192);
        __builtin_amdgcn_s_setprio(1);
        acc0 = __builtin_amdgcn_mfma_i32_16x16x64_i8(a[0][0], bfr[0], acc0, 0, 0, 0);
        acc1 = __builtin_amdgcn_mfma_i32_16x16x64_i8(a[1][0], bfr[0], acc1, 0, 0, 0);
        bfr[0] = *(const i32x4*)(sp + 256);
        acc0 = __builtin_amdgcn_mfma_i32_16x16x64_i8(a[0][1], bfr[1], acc0, 0, 0, 0);
        acc1 = __builtin_amdgcn_mfma_i32_16x16x64_i8(a[1][1], bfr[1], acc1, 0, 0, 0);
        bfr[1] = *(const i32x4*)(sp + 320);
        acc0 = __builtin_amdgcn_mfma_i32_16x16x64_i8(a[0][2], bfr[2], acc0, 0, 0, 0);
        acc1 = __builtin_amdgcn_mfma_i32_16x16x64_i8(a[1][2], bfr[2], acc1, 0, 0, 0);
        bfr[2] = *(const i32x4*)(sp + 384);
        acc0 = __builtin_amdgcn_mfma_i32_16x16x64_i8(a[0][3], bfr[3], acc0, 0, 0, 0);
        acc1 = __builtin_amdgcn_mfma_i32_16x16x64_i8(a[1][3], bfr[3], acc1, 0, 0, 0);
        bfr[3] = *(const i32x4*)(sp + 448);
        acc0 = __builtin_amdgcn_mfma_i32_16x16x64_i8(a[0][4], bfr[0], acc0, 0, 0, 0);
        acc1 = __builtin_amdgcn_mfma_i32_16x16x64_i8(a[1][4], bfr[0], acc1, 0, 0, 0);
        acc0 = __builtin_amdgcn_mfma_i32_16x16x64_i8(a[0][5], bfr[1], acc0, 0, 0, 0);
        acc1 = __builtin_amdgcn_mfma_i32_16x16x64_i8(a[1][5], bfr[1], acc1, 0, 0, 0);
        acc0 = __builtin_amdgcn_mfma_i32_16x16x64_i8(a[0][6], bfr[2], acc0, 0, 0, 0);
        acc1 = __builtin_amdgcn_mfma_i32_16x16x64_i8(a[1][6], bfr[2], acc1, 0, 0, 0);
        acc0 = __builtin_amdgcn_mfma_i32_16x16x64_i8(a[0][7], bfr[3], acc0, 0, 0, 0);
        acc1 = __builtin_amdgcn_mfma_i32_16x16x64_i8(a[1][7], bfr[3], acc1, 0, 0, 0);
        __builtin_amdgcn_s_setprio(0);

        // args (consume xi), then reload xi for next step (latency hidden by rest of step)
        float g0[4], g1[4];
#pragma unroll
        for (int r = 0; r < 4; ++r) g0[r] = fmaf((float)acc0[r], gs2, xi0[r]);
#pragma unroll
        for (int r = 0; r < 4; ++r) g1[r] = fmaf((float)acc1[r], gs2, xi1[r]);
        xi0 = *(const f32x4*)(pnext);
        xi1 = *(const f32x4*)(pnext + 16);

        f32x4 ho0, ho1;
        unsigned m0[4], m1[4];
#pragma unroll
        for (int r = 0; r < 4; ++r) {
            float e = __builtin_amdgcn_exp2f(g0[r]);
            float rc = __builtin_amdgcn_rcpf(1.0f + e);
            float t = fmaf(rc, -254.0f, 127.0f);
            float mm = t + 12582912.0f;                  // RNE, |t| <= 127
            m0[r] = __float_as_uint(mm);
            ho0[r] = (mm - 12582912.0f) * (1.0f / 127.0f);
        }
#pragma unroll
        for (int r = 0; r < 4; ++r) {
            float e = __builtin_amdgcn_exp2f(g1[r]);
            float rc = __builtin_amdgcn_rcpf(1.0f + e);
            float t = fmaf(rc, -254.0f, 127.0f);
            float mm = t + 12582912.0f;
            m1[r] = __float_as_uint(mm);
            ho1[r] = (mm - 12582912.0f) * (1.0f / 127.0f);
        }
        // pack 4 int8 state bytes per M-tile via v_perm
        unsigned p01 = __builtin_amdgcn_perm(m0[1], m0[0], 0x00000400u);
        unsigned p23 = __builtin_amdgcn_perm(m0[3], m0[2], 0x00000400u);
        unsigned pk0 = __builtin_amdgcn_perm(p23, p01, 0x05040100u);
        unsigned q01 = __builtin_amdgcn_perm(m1[1], m1[0], 0x00000400u);
        unsigned q23 = __builtin_amdgcn_perm(m1[3], m1[2], 0x00000400u);
        unsigned pk1 = __builtin_amdgcn_perm(q23, q01, 0x05040100u);

        *(f32x4*)(pbase) = ho0;                               // h out (dwordx4)
        *(f32x4*)(pbase + 16) = ho1;
        signed char* sw = &st[pp ^ 1][l15][n0 + q * 4];
        *(unsigned*)(sw) = pk0;                               // 4 state bytes, M-tile 0
        *(unsigned*)(sw + 16) = pk1;                          // 4 state bytes, M-tile 1

        pbase = pnext;
        // LDS-only barrier: don't drain vmcnt (out stores / xi loads stay in flight)
        asm volatile("s_waitcnt lgkmcnt(0)" ::: "memory");
        __builtin_amdgcn_s_barrier();
        __builtin_amdgcn_sched_barrier(0);
        pp ^= 1;
    }
}

extern "C" void kernel_launch(void* const* d_in, const int* in_sizes, int n_in,
                              void* d_out, int out_size, void* d_ws, size_t ws_size,
                              hipStream_t stream) {
    const float* x     = (const float*)d_in[0];
    const float* wri_f = (const float*)d_in[1];
    const float* wrh_f = (const float*)d_in[2];
    const float* b_f   = (const float*)d_in[3];
    const float* wri_b = (const float*)d_in[4];
    const float* wrh_b = (const float*)d_in[5];
    const float* b_b   = (const float*)d_in[6];
    float* out = (float*)d_out;
    char* ws = (char*)d_ws;

    size_t need = WS_XQ_OFF + XQ_BYTES + WRIT_BYTES + WRHT_BYTES;
    if (ws_size < need) return;

    unsigned* thrbits = (unsigned*)ws;
    signed char* xq   = (signed char*)(ws + WS_XQ_OFF);
    signed char* writ = xq + XQ_BYTES;
    signed char* wrht = writ + WRIT_BYTES;

    hipMemsetAsync(thrbits, 0, 8, stream);
    k_absmax<<<dim3(64, 2), 256, 0, stream>>>(wri_f, wrh_f, wri_b, wrh_b, thrbits);
    k_quant_w<<<256, 256, 0, stream>>>(wri_f, wrh_f, wri_b, wrh_b, thrbits, writ, wrht);
    k_quant_x<<<16384, 256, 0, stream>>>(x, xq);
    k_gemm_xif<<<2048, 256, 0, stream>>>(xq, writ, b_f, b_b, thrbits, out);
    k_rnn<<<2, 1024, 0, stream>>>(wrht, thrbits, out);
}

// Round 6
// 1626.793 us; speedup vs baseline: 2.4397x; 2.0631x over previous
//
#include <hip/hip_runtime.h>
#include <stdint.h>

typedef int i32x4 __attribute__((ext_vector_type(4)));

#define TWO_LOG2E 2.8853900817779268f

// ---------------- ws layout ----------------
// [0,8)            : thrbits[2] (uint, atomicMax of |w| bits)
// [4096, +16MB)    : Xq  [32768][512] int8
// then             : WriT [1024][512] int8  (n = dir*512 + j, k = i)
// then             : WrhT [2][512][512] int8 (row j, col i)
#define WS_XQ_OFF   4096
#define XQ_BYTES    ((size_t)32768 * 512)
#define WRIT_BYTES  ((size_t)1024 * 512)
#define WRHT_BYTES  ((size_t)2 * 512 * 512)

// Signed int8 dot4 via the BUILTIN only. Round 5 proved the raw
// "v_dot4_i32_i8" mnemonic assembles on gfx950 but computes different
// (wrong-sign) semantics than the builtin's lowering — never hand-pick it.
static __device__ __forceinline__ int dot4(int a, int b, int c) {
#if __has_builtin(__builtin_amdgcn_sdot4)
    return __builtin_amdgcn_sdot4(a, b, c, false);
#else
    int r = c;
    r += (int)(signed char)(a) * (int)(signed char)(b);
    r += (int)(signed char)(a >> 8) * (int)(signed char)(b >> 8);
    r += (int)(signed char)(a >> 16) * (int)(signed char)(b >> 16);
    r += (int)(signed char)(a >> 24) * (int)(signed char)(b >> 24);
    return r;
#endif
}

// ---------------- threshold = max |w| over [w_ri; w_rh] per direction ----------------
__global__ __launch_bounds__(256) void k_absmax(const float* __restrict__ wri_f,
                                                const float* __restrict__ wrh_f,
                                                const float* __restrict__ wri_b,
                                                const float* __restrict__ wrh_b,
                                                unsigned* thrbits) {
    int dir = blockIdx.y;
    const float* a = dir ? wri_b : wri_f;
    const float* c = dir ? wrh_b : wrh_f;
    float m = 0.f;
    for (int i = blockIdx.x * 256 + threadIdx.x; i < 512 * 512; i += gridDim.x * 256) {
        m = fmaxf(m, fabsf(a[i]));
        m = fmaxf(m, fabsf(c[i]));
    }
    __shared__ float red[256];
    red[threadIdx.x] = m;
    __syncthreads();
    for (int s = 128; s > 0; s >>= 1) {
        if (threadIdx.x < s) red[threadIdx.x] = fmaxf(red[threadIdx.x], red[threadIdx.x + s]);
        __syncthreads();
    }
    if (threadIdx.x == 0) atomicMax(&thrbits[dir], __float_as_uint(red[0]));
}

// ---------------- quantize weights + transpose (WT[j][i] = round(W[i][j]/s)) ----------------
__global__ __launch_bounds__(256) void k_quant_w(const float* __restrict__ wri_f,
                                                 const float* __restrict__ wrh_f,
                                                 const float* __restrict__ wri_b,
                                                 const float* __restrict__ wrh_b,
                                                 const unsigned* __restrict__ thrbits,
                                                 signed char* __restrict__ writ,
                                                 signed char* __restrict__ wrht) {
    int id = blockIdx.x;             // 256 blocks
    int dir = id & 1;
    int which = (id >> 1) & 1;       // 0 = ri, 1 = rh
    int tile = id >> 2;              // 0..63  (8x8 tiles of 64x64)
    int ti = tile >> 3, tj = tile & 7;
    const float* src = which ? (dir ? wrh_b : wrh_f) : (dir ? wri_b : wri_f);
    signed char* dst = which ? (wrht + (size_t)dir * 512 * 512) : (writ + (size_t)dir * 512 * 512);
    float s = __uint_as_float(thrbits[dir]) / 127.0f;
    __shared__ signed char t8[64][68];
    int tx = threadIdx.x & 63, ty = threadIdx.x >> 6;
    int i0 = ti * 64, j0 = tj * 64;
#pragma unroll
    for (int r = 0; r < 16; ++r) {
        int il = r * 4 + ty;
        float w = src[(size_t)(i0 + il) * 512 + j0 + tx];
        float q = rintf(w / s);
        q = fminf(fmaxf(q, -127.f), 127.f);
        t8[il][tx] = (signed char)(int)q;
    }
    __syncthreads();
#pragma unroll
    for (int r = 0; r < 16; ++r) {
        int jl = r * 4 + ty;
        dst[(size_t)(j0 + jl) * 512 + i0 + tx] = t8[tx][jl];  // WT[j][i]
    }
}

// ---------------- quantize inputs: xq = round(clip(x,-1,1)*127) ----------------
__global__ __launch_bounds__(256) void k_quant_x(const float* __restrict__ x,
                                                 signed char* __restrict__ xq) {
    int i = blockIdx.x * 256 + threadIdx.x;   // one float4 per thread, 16384 blocks
    float4 v = ((const float4*)x)[i];
    int q0 = (int)rintf(fminf(fmaxf(v.x, -1.f), 1.f) * 127.f);
    int q1 = (int)rintf(fminf(fmaxf(v.y, -1.f), 1.f) * 127.f);
    int q2 = (int)rintf(fminf(fmaxf(v.z, -1.f), 1.f) * 127.f);
    int q3 = (int)rintf(fminf(fmaxf(v.w, -1.f), 1.f) * 127.f);
    ((int*)xq)[i] = (q0 & 255) | ((q1 & 255) << 8) | ((q2 & 255) << 16) | ((q3 & 255) << 24);
}

// ---------------- GEMM: out[t*16+b][n] = (Xq . WriT[n]) * gs2 + b[n]*2log2e ----------------
__global__ __launch_bounds__(256, 2) void k_gemm_xif(const signed char* __restrict__ xq,
                                                     const signed char* __restrict__ writ,
                                                     const float* __restrict__ b_f,
                                                     const float* __restrict__ b_b,
                                                     const unsigned* __restrict__ thrbits,
                                                     float* __restrict__ out) {
    int bid = blockIdx.x;        // 2048 = 256 Mtiles * 8 Ntiles
    int mt8 = bid >> 3;
    int nt8 = bid & 7;
    int w = threadIdx.x >> 6, lane = threadIdx.x & 63;
    int l15 = lane & 15, q = lane >> 4;
    int M0 = mt8 * 128 + (w >> 1) * 64;
    int N0 = nt8 * 128 + (w & 1) * 64;
    int dir = N0 >> 9;
    float thr = __uint_as_float(thrbits[dir]);
    float gs2 = thr * (TWO_LOG2E / (127.f * 127.f));
    const float* bp = dir ? b_b : b_f;
    float bi2[4];
#pragma unroll
    for (int nt = 0; nt < 4; ++nt)
        bi2[nt] = bp[(N0 & 511) + nt * 16 + l15] * TWO_LOG2E;

    i32x4 acc[4][4];
#pragma unroll
    for (int mt = 0; mt < 4; ++mt)
#pragma unroll
        for (int nt = 0; nt < 4; ++nt)
            acc[mt][nt] = (i32x4){0, 0, 0, 0};

#pragma unroll
    for (int kb = 0; kb < 8; ++kb) {
        i32x4 af[4], bf[4];
#pragma unroll
        for (int mt = 0; mt < 4; ++mt)
            af[mt] = *(const i32x4*)(xq + (size_t)(M0 + mt * 16 + l15) * 512 + kb * 64 + q * 16);
#pragma unroll
        for (int nt = 0; nt < 4; ++nt)
            bf[nt] = *(const i32x4*)(writ + (size_t)(N0 + nt * 16 + l15) * 512 + kb * 64 + q * 16);
#pragma unroll
        for (int mt = 0; mt < 4; ++mt)
#pragma unroll
            for (int nt = 0; nt < 4; ++nt)
                acc[mt][nt] = __builtin_amdgcn_mfma_i32_16x16x64_i8(af[mt], bf[nt], acc[mt][nt], 0, 0, 0);
    }
#pragma unroll
    for (int mt = 0; mt < 4; ++mt)
#pragma unroll
        for (int nt = 0; nt < 4; ++nt)
#pragma unroll
            for (int r = 0; r < 4; ++r) {
                int row = M0 + mt * 16 + q * 4 + r;
                int col = N0 + nt * 16 + l15;
                out[(size_t)row * 1024 + col] = fmaf((float)acc[mt][nt][r], gs2, bi2[nt]);
            }
}

// ---------------- persistent recurrence: 1 WG per (dir, batch), 32 WGs ----------------
// dot4 GEMV: each of 512 lanes owns one output column n; its W_rh row (512 B) lives
// in 128 arch VGPRs. __launch_bounds__(512, 1): only 32 WGs exist for 256 CUs, so
// multi-wave occupancy is irrelevant — give the RA the full register budget so it
// does NOT spill the weight array to AGPRs (round 2's +512 cyc/step v_accvgpr_read
// storm at launch_bounds(512,2)). Defs additionally pinned to the "v" class.
// gate_arg = acc*gs2 + XiF (XiF read from out, overwritten with h afterwards)
// h127 = rint(127*tanh) = rint(127 - 254 / (1 + exp2(arg)))
__global__ __launch_bounds__(512, 1) void k_rnn(const signed char* __restrict__ wrht,
                                                const unsigned* __restrict__ thrbits,
                                                float* __restrict__ out) {
    int bid = blockIdx.x;           // 32
    int dir = bid >> 4, batch = bid & 15;
    int n = threadIdx.x;            // this lane's output column
    float thr = __uint_as_float(thrbits[dir]);
    float gs2 = thr * (TWO_LOG2E / (127.f * 127.f));
    const signed char* wq = wrht + (size_t)dir * 512 * 512 + (size_t)n * 512;

    // W row resident in 128 arch VGPRs: 32 x i32x4, static indexing only
    i32x4 w[32];
#pragma unroll
    for (int i = 0; i < 32; ++i) {
        w[i] = *(const i32x4*)(wq + i * 16);
        asm("" : "+v"(w[i]));        // pin def to arch-VGPR class (no AGPR home)
    }

    __shared__ __align__(16) signed char st[2][512];
    if (threadIdx.x < 256) ((int*)st)[threadIdx.x] = 0;
    __syncthreads();

    int t0 = dir ? 2047 : 0;
    const long long rowstride = (long long)(dir ? -1 : 1) * 16 * 1024;
    float* prow = out + (size_t)t0 * 16 * 1024 + (size_t)batch * 1024 + (size_t)dir * 512 + n;

    float xi = *prow;
    int pp = 0;
    for (int step = 0; step < 2048; ++step) {
        // prefetch next step's XiF (hides HBM/L2 latency under the dot4 stream)
        float* pnext = prow + ((step + 1 < 2048) ? rowstride : 0);
        float xin = *pnext;

        int acc0 = 0, acc1 = 0, acc2 = 0, acc3 = 0;
#pragma unroll
        for (int kb = 0; kb < 32; ++kb) {
            i32x4 s4 = *(const i32x4*)&st[pp][kb * 16];  // broadcast read, conflict-free
            acc0 = dot4(w[kb][0], s4[0], acc0);
            acc1 = dot4(w[kb][1], s4[1], acc1);
            acc2 = dot4(w[kb][2], s4[2], acc2);
            acc3 = dot4(w[kb][3], s4[3], acc3);
        }
        int acc = (acc0 + acc1) + (acc2 + acc3);

        float arg = fmaf((float)acc, gs2, xi);
        float e = __builtin_amdgcn_exp2f(arg);
        float r = __builtin_amdgcn_rcpf(1.0f + e);
        float h127 = rintf(fmaf(r, -254.0f, 127.0f));
        *prow = h127 * (1.0f / 127.0f);                  // h out (coalesced, all 64 lanes)
        st[pp ^ 1][n] = (signed char)(int)h127;          // next state byte

        xi = xin;
        prow = pnext;
        // LDS-only barrier: don't drain vmcnt (the h-store can stay in flight)
        asm volatile("s_waitcnt lgkmcnt(0)" ::: "memory");
        __builtin_amdgcn_s_barrier();
        __builtin_amdgcn_sched_barrier(0);
        pp ^= 1;
    }
}

extern "C" void kernel_launch(void* const* d_in, const int* in_sizes, int n_in,
                              void* d_out, int out_size, void* d_ws, size_t ws_size,
                              hipStream_t stream) {
    const float* x     = (const float*)d_in[0];
    const float* wri_f = (const float*)d_in[1];
    const float* wrh_f = (const float*)d_in[2];
    const float* b_f   = (const float*)d_in[3];
    const float* wri_b = (const float*)d_in[4];
    const float* wrh_b = (const float*)d_in[5];
    const float* b_b   = (const float*)d_in[6];
    float* out = (float*)d_out;
    char* ws = (char*)d_ws;

    size_t need = WS_XQ_OFF + XQ_BYTES + WRIT_BYTES + WRHT_BYTES;
    if (ws_size < need) return;

    unsigned* thrbits = (unsigned*)ws;
    signed char* xq   = (signed char*)(ws + WS_XQ_OFF);
    signed char* writ = xq + XQ_BYTES;
    signed char* wrht = writ + WRIT_BYTES;

    hipMemsetAsync(thrbits, 0, 8, stream);
    k_absmax<<<dim3(64, 2), 256, 0, stream>>>(wri_f, wrh_f, wri_b, wrh_b, thrbits);
    k_quant_w<<<256, 256, 0, stream>>>(wri_f, wrh_f, wri_b, wrh_b, thrbits, writ, wrht);
    k_quant_x<<<16384, 256, 0, stream>>>(x, xq);
    k_gemm_xif<<<2048, 256, 0, stream>>>(xq, writ, b_f, b_b, thrbits, out);
    k_rnn<<<32, 512, 0, stream>>>(wrht, thrbits, out);
}